// Round 1
// baseline (1703.184 us; speedup 1.0000x reference)
//
#include <hip/hip_runtime.h>

constexpr int HH   = 4;    // heads
constexpr int DINC = 128;  // input feature dim
constexpr int OUTC = 128;  // output feature dim (H*D)

typedef __attribute__((ext_vector_type(4))) float        f32x4;
typedef __attribute__((ext_vector_type(2))) float        f32x2;
typedef __attribute__((ext_vector_type(4))) unsigned int u32x4;
typedef __attribute__((ext_vector_type(8))) short        bf16x8;

__device__ __forceinline__ float leaky(float x){ return x >= 0.f ? x : 0.2f*x; }
// monotone float->uint key for atomicMax-based segment max
__device__ __forceinline__ unsigned fkey(float f){ unsigned u=__float_as_uint(f); return (u&0x80000000u)? ~u : (u|0x80000000u); }
__device__ __forceinline__ float kf(unsigned k){ return __uint_as_float((k&0x80000000u)? (k^0x80000000u) : ~k); }
__device__ __forceinline__ short f2bf(float f){ unsigned u=__float_as_uint(f); unsigned r=(u + 0x7FFFu + ((u>>16)&1u))>>16; return (short)r; }

// ---------------- K0: tiny prep (1 block) ----------------
// v_x[h][k] = sum_d attn_x[h][d] * W_x[h*32+d][k]; W transposes; W_edge -> bf16
__global__ __launch_bounds__(256) void prep_kernel(
    const float* __restrict__ Ws, const float* __restrict__ Wd, const float* __restrict__ We,
    const float* __restrict__ as_, const float* __restrict__ ad_, const float* __restrict__ ae_,
    float* __restrict__ vs, float* __restrict__ vd, float* __restrict__ ve,
    float* __restrict__ Wts, float* __restrict__ Wtd, float* __restrict__ Wte,
    unsigned short* __restrict__ Wbf)
{
  int t = threadIdx.x;
  for (int idx = t; idx < HH*DINC; idx += 256) {
    int h = idx >> 7, k = idx & 127;
    float s1=0.f, s2=0.f, s3=0.f;
    for (int d=0; d<32; ++d) {
      int r = h*32 + d;
      float a1 = as_[h*32+d], a2 = ad_[h*32+d], a3 = ae_[h*32+d];
      s1 += a1 * Ws[r*DINC + k];
      s2 += a2 * Wd[r*DINC + k];
      s3 += a3 * We[r*DINC + k];
    }
    vs[idx] = s1; vd[idx] = s2; ve[idx] = s3;
  }
  for (int idx = t; idx < DINC*OUTC; idx += 256) {
    int j = idx >> 7, k = idx & 127;
    Wts[k*OUTC + j] = Ws[idx];
    Wtd[k*OUTC + j] = Wd[idx];
    Wte[k*OUTC + j] = We[idx];
    Wbf[idx] = (unsigned short)f2bf(We[idx]);
  }
}

// ---------------- K1: per-node h_src, h_dst(->out), e_src, e_dst ----------------
#define NT 32
__global__ __launch_bounds__(256) void node_kernel(
    const float* __restrict__ X, const float* __restrict__ Wts, const float* __restrict__ Wtd,
    const float* __restrict__ vs, const float* __restrict__ vd,
    float* __restrict__ hsrc, float* __restrict__ out,
    float* __restrict__ esrc, float* __restrict__ edst, int N)
{
  __shared__ float Xs[NT][DINC+1];     // +1 pad: conflict-free column reads in e-phase
  __shared__ float vsh[2][HH][DINC];
  int t = threadIdx.x;
  int n0 = blockIdx.x * NT;

  for (int idx = t; idx < NT*DINC; idx += 256) {
    int n = idx >> 7, k = idx & 127;
    float v = 0.f;
    if (n0 + n < N) v = X[(long)(n0+n)*DINC + k];
    Xs[n][k] = v;
  }
  for (int idx = t; idx < HH*DINC; idx += 256) {
    ((float*)vsh)[idx]           = vs[idx];
    ((float*)vsh)[HH*DINC + idx] = vd[idx];
  }
  __syncthreads();

  int mat = t >> 7;            // 0: h_src, 1: h_dst
  int jq  = (t & 31) * 4;      // output col group
  int r0  = (t >> 5) & 3;      // node subset
  const float* Wt = mat ? Wtd : Wts;
  f32x4 acc[8];
  #pragma unroll
  for (int i=0;i<8;i++) acc[i] = (f32x4){0,0,0,0};

  for (int k=0; k<DINC; ++k) {
    f32x4 w4 = *(const f32x4*)(Wt + k*OUTC + jq);
    #pragma unroll
    for (int i=0;i<8;i++) {
      float x = Xs[r0 + i*4][k];
      acc[i] += w4 * x;
    }
  }
  float* dstp = mat ? out : hsrc;
  #pragma unroll
  for (int i=0;i<8;i++) {
    int n = n0 + r0 + i*4;
    if (n < N) *(f32x4*)(dstp + (long)n*OUTC + jq) = acc[i];
  }
  // e_src / e_dst: one thread per (path, head, local node)
  int path = t >> 7, h = (t >> 5) & 3, nl = t & 31;
  int n = n0 + nl;
  if (n < N) {
    const float* vv = vsh[path][h];
    float s = 0.f;
    for (int k=0; k<DINC; ++k) s += Xs[nl][k] * vv[k];
    (path ? edst : esrc)[(long)n*HH + h] = s;
  }
}

// ---------------- K2: per-edge logits e_edge + segment max (atomicMax on keys) ----------------
__global__ __launch_bounds__(256) void edge_logits(
    const float* __restrict__ Xe, const float* __restrict__ ve,
    const float* __restrict__ esrc, const float* __restrict__ edst,
    const int* __restrict__ src, const int* __restrict__ dst,
    float* __restrict__ eedge, unsigned* __restrict__ m1, unsigned* __restrict__ m2, int E)
{
  int t = threadIdx.x;
  int wid = t >> 6, lane = t & 63;
  long e = (long)blockIdx.x * 8 + wid*2 + (lane >> 5);
  int k4 = (lane & 31) * 4;
  float a0=0.f, a1=0.f, a2=0.f, a3=0.f;
  if (e < E) {
    f32x4 x4 = *(const f32x4*)(Xe + e*DINC + k4);
    f32x4 v0 = *(const f32x4*)(ve + 0*DINC + k4);
    f32x4 v1 = *(const f32x4*)(ve + 1*DINC + k4);
    f32x4 v2 = *(const f32x4*)(ve + 2*DINC + k4);
    f32x4 v3 = *(const f32x4*)(ve + 3*DINC + k4);
    a0 = x4[0]*v0[0]+x4[1]*v0[1]+x4[2]*v0[2]+x4[3]*v0[3];
    a1 = x4[0]*v1[0]+x4[1]*v1[1]+x4[2]*v1[2]+x4[3]*v1[3];
    a2 = x4[0]*v2[0]+x4[1]*v2[1]+x4[2]*v2[2]+x4[3]*v2[3];
    a3 = x4[0]*v3[0]+x4[1]*v3[1]+x4[2]*v3[2]+x4[3]*v3[3];
  }
  #pragma unroll
  for (int s = 1; s <= 16; s <<= 1) {
    a0 += __shfl_xor(a0, s, 64);
    a1 += __shfl_xor(a1, s, 64);
    a2 += __shfl_xor(a2, s, 64);
    a3 += __shfl_xor(a3, s, 64);
  }
  if ((lane & 31) == 0 && e < E) {
    int s_ = src[e], d_ = dst[e];
    f32x4 es = *(const f32x4*)(esrc + (long)s_*HH);
    f32x4 ed = *(const f32x4*)(edst + (long)d_*HH);
    f32x4 ee; ee[0]=a0; ee[1]=a1; ee[2]=a2; ee[3]=a3;
    *(f32x4*)(eedge + e*HH) = ee;
    #pragma unroll
    for (int h=0; h<HH; ++h) {
      float e1 = leaky(es[h] + ed[h]);
      float e2 = leaky(ee[h] + ed[h]);
      atomicMax(m1 + (long)d_*HH + h, fkey(e1));
      atomicMax(m2 + (long)d_*HH + h, fkey(e2));
    }
  }
}

// ---------------- K2b: h_edge = Xe(bf16) @ W_edge^T(bf16), f32 out (MFMA) ----------------
__global__ __launch_bounds__(256) void hedge_gemm(
    const float* __restrict__ Xe, const unsigned short* __restrict__ Wbf,
    float* __restrict__ Hedge, int E)
{
  int wid  = (blockIdx.x * blockDim.x + threadIdx.x) >> 6;
  int lane = threadIdx.x & 63;
  long base = (long)wid * 16;
  if (base >= E) return;
  int r16 = lane & 15;   // A row / B col sub-index
  int g   = lane >> 4;   // k-group
  f32x4 acc[8];
  #pragma unroll
  for (int nt=0; nt<8; ++nt) acc[nt] = (f32x4){0,0,0,0};

  #pragma unroll
  for (int kc=0; kc<4; ++kc) {
    long row = base + r16; if (row >= E) row = E-1;
    const float* ap = Xe + row*DINC + kc*32 + g*8;
    f32x4 x0 = *(const f32x4*)ap;
    f32x4 x1 = *(const f32x4*)(ap + 4);
    bf16x8 af;
    af[0]=f2bf(x0[0]); af[1]=f2bf(x0[1]); af[2]=f2bf(x0[2]); af[3]=f2bf(x0[3]);
    af[4]=f2bf(x1[0]); af[5]=f2bf(x1[1]); af[6]=f2bf(x1[2]); af[7]=f2bf(x1[3]);
    #pragma unroll
    for (int nt=0; nt<8; ++nt) {
      const unsigned short* bp = Wbf + (nt*16 + r16)*DINC + kc*32 + g*8;
      bf16x8 bf = *(const bf16x8*)bp;
      acc[nt] = __builtin_amdgcn_mfma_f32_16x16x32_bf16(af, bf, acc[nt], 0, 0, 0);
    }
  }
  // D layout: col = lane&15 (n), row = (lane>>4)*4 + reg (m)
  #pragma unroll
  for (int nt=0; nt<8; ++nt) {
    #pragma unroll
    for (int r=0; r<4; ++r) {
      long e = base + g*4 + r;
      if (e < E) Hedge[e*OUTC + nt*16 + r16] = acc[nt][r];
    }
  }
}

// ---------------- K4: segment exp-sums ----------------
__global__ __launch_bounds__(256) void edge_sums(
    const float* __restrict__ eedge, const float* __restrict__ esrc, const float* __restrict__ edst,
    const int* __restrict__ src, const int* __restrict__ dst,
    const unsigned* __restrict__ m1, const unsigned* __restrict__ m2,
    float* __restrict__ s1, float* __restrict__ s2, int E)
{
  int e = blockIdx.x * 256 + threadIdx.x;
  if (e >= E) return;
  int s_ = src[e], d_ = dst[e];
  f32x4 es = *(const f32x4*)(esrc + (long)s_*HH);
  f32x4 ed = *(const f32x4*)(edst + (long)d_*HH);
  f32x4 ee = *(const f32x4*)(eedge + (long)e*HH);
  u32x4 k1 = *(const u32x4*)(m1 + (long)d_*HH);
  u32x4 k2 = *(const u32x4*)(m2 + (long)d_*HH);
  #pragma unroll
  for (int h=0; h<HH; ++h) {
    float ex1 = __expf(leaky(es[h] + ed[h]) - kf(k1[h]));
    float ex2 = __expf(leaky(ee[h] + ed[h]) - kf(k2[h]));
    atomicAdd(s1 + (long)d_*HH + h, ex1);
    atomicAdd(s2 + (long)d_*HH + h, ex2);
  }
}

// ---------------- K5: aggregation out[dst] += a1*h_src[src] + a2*h_edge[e] ----------------
template<int RECOMP>
__global__ __launch_bounds__(256) void aggregate(
    const float* __restrict__ Hedge, const float* __restrict__ Xe, const float* __restrict__ Wte,
    const float* __restrict__ hsrc, const float* __restrict__ eedge,
    const float* __restrict__ esrc, const float* __restrict__ edst,
    const int* __restrict__ src, const int* __restrict__ dst,
    const unsigned* __restrict__ m1, const unsigned* __restrict__ m2,
    const float* __restrict__ s1, const float* __restrict__ s2,
    float* __restrict__ out, int E)
{
  int t = threadIdx.x;
  long e = (long)blockIdx.x * 4 + (t >> 6);
  if (e >= E) return;
  int j2 = (t & 63) * 2;
  int h  = j2 >> 5;
  int s_ = src[e], d_ = dst[e];
  float esg = esrc[(long)s_*HH + h];
  float edg = edst[(long)d_*HH + h];
  float ee  = eedge[e*HH + h];
  float a1 = __expf(leaky(esg + edg) - kf(m1[(long)d_*HH + h])) / s1[(long)d_*HH + h];
  float a2 = __expf(leaky(ee  + edg) - kf(m2[(long)d_*HH + h])) / s2[(long)d_*HH + h];
  f32x2 hs = *(const f32x2*)(hsrc + (long)s_*OUTC + j2);
  f32x2 he;
  if (RECOMP) {
    float h0 = 0.f, h1 = 0.f;
    for (int k=0; k<DINC; ++k) {
      float x = Xe[e*DINC + k];
      f32x2 w = *(const f32x2*)(Wte + k*OUTC + j2);
      h0 += x * w[0]; h1 += x * w[1];
    }
    he[0] = h0; he[1] = h1;
  } else {
    he = *(const f32x2*)(Hedge + e*OUTC + j2);
  }
  atomicAdd(out + (long)d_*OUTC + j2,     a1*hs[0] + a2*he[0]);
  atomicAdd(out + (long)d_*OUTC + j2 + 1, a1*hs[1] + a2*he[1]);
}

extern "C" void kernel_launch(void* const* d_in, const int* in_sizes, int n_in,
                              void* d_out, int out_size, void* d_ws, size_t ws_size,
                              hipStream_t stream) {
  const float* X   = (const float*)d_in[0];
  const float* Xe  = (const float*)d_in[1];
  const float* Ws  = (const float*)d_in[2];
  const float* Wd  = (const float*)d_in[3];
  const float* We  = (const float*)d_in[4];
  const float* as_ = (const float*)d_in[5];
  const float* ad_ = (const float*)d_in[6];
  const float* ae_ = (const float*)d_in[7];
  const int* src   = (const int*)d_in[8];
  const int* dst   = (const int*)d_in[9];
  int N = in_sizes[0] / DINC;
  int E = in_sizes[8];
  float* out = (float*)d_out;

  char* ws = (char*)d_ws;
  size_t o_hsrc  = 0;
  size_t o_esrc  = o_hsrc  + (size_t)N*OUTC*4;
  size_t o_edst  = o_esrc  + (size_t)N*HH*4;
  size_t o_eedge = o_edst  + (size_t)N*HH*4;
  size_t o_m1    = o_eedge + (size_t)E*HH*4;
  size_t o_m2    = o_m1    + (size_t)N*HH*4;
  size_t o_s1    = o_m2    + (size_t)N*HH*4;
  size_t o_s2    = o_s1    + (size_t)N*HH*4;
  size_t o_vs    = o_s2    + (size_t)N*HH*4;
  size_t o_vd    = o_vs    + (size_t)HH*DINC*4;
  size_t o_ve    = o_vd    + (size_t)HH*DINC*4;
  size_t o_wts   = o_ve    + (size_t)HH*DINC*4;
  size_t o_wtd   = o_wts   + (size_t)DINC*OUTC*4;
  size_t o_wte   = o_wtd   + (size_t)DINC*OUTC*4;
  size_t o_wbf   = o_wte   + (size_t)DINC*OUTC*4;
  size_t o_hedge = o_wbf   + (size_t)DINC*OUTC*2;
  size_t req_full = o_hedge + (size_t)E*OUTC*4;
  bool full = (ws_size >= req_full);

  float* hsrc  = (float*)(ws + o_hsrc);
  float* esrc  = (float*)(ws + o_esrc);
  float* edstp = (float*)(ws + o_edst);
  float* eedge = (float*)(ws + o_eedge);
  unsigned* m1 = (unsigned*)(ws + o_m1);
  unsigned* m2 = (unsigned*)(ws + o_m2);
  float* s1    = (float*)(ws + o_s1);
  float* s2    = (float*)(ws + o_s2);
  float* vs    = (float*)(ws + o_vs);
  float* vd    = (float*)(ws + o_vd);
  float* ve    = (float*)(ws + o_ve);
  float* wts   = (float*)(ws + o_wts);
  float* wtd   = (float*)(ws + o_wtd);
  float* wte   = (float*)(ws + o_wte);
  unsigned short* wbf = (unsigned short*)(ws + o_wbf);
  float* hedge = (float*)(ws + o_hedge);

  // zero the max-keys (0 < key(x) for all finite x) and the exp-sums
  hipMemsetAsync(ws + o_m1, 0, (size_t)N*HH*4*4, stream);

  prep_kernel<<<1, 256, 0, stream>>>(Ws, Wd, We, as_, ad_, ae_, vs, vd, ve, wts, wtd, wte, wbf);
  node_kernel<<<(N + NT - 1)/NT, 256, 0, stream>>>(X, wts, wtd, vs, vd, hsrc, out, esrc, edstp, N);
  edge_logits<<<(E + 7)/8, 256, 0, stream>>>(Xe, ve, esrc, edstp, src, dst, eedge, m1, m2, E);
  if (full)
    hedge_gemm<<<(E + 63)/64, 256, 0, stream>>>(Xe, wbf, hedge, E);
  edge_sums<<<(E + 255)/256, 256, 0, stream>>>(eedge, esrc, edstp, src, dst, m1, m2, s1, s2, E);
  if (full)
    aggregate<0><<<(E + 3)/4, 256, 0, stream>>>(hedge, Xe, wte, hsrc, eedge, esrc, edstp, src, dst, m1, m2, s1, s2, out, E);
  else
    aggregate<1><<<(E + 3)/4, 256, 0, stream>>>(hedge, Xe, wte, hsrc, eedge, esrc, edstp, src, dst, m1, m2, s1, s2, out, E);
}

// Round 2
// 855.301 us; speedup vs baseline: 1.9913x; 1.9913x over previous
//
#include <hip/hip_runtime.h>

constexpr int HH   = 4;    // heads
constexpr int DINC = 128;  // input feature dim
constexpr int OUTC = 128;  // output feature dim (H*D)

typedef __attribute__((ext_vector_type(4))) float        f32x4;
typedef __attribute__((ext_vector_type(2))) float        f32x2;
typedef __attribute__((ext_vector_type(4))) unsigned int u32x4;

__device__ __forceinline__ float leaky(float x){ return x >= 0.f ? x : 0.2f*x; }
__device__ __forceinline__ short f2bf(float f){ unsigned u=__float_as_uint(f); unsigned r=(u + 0x7FFFu + ((u>>16)&1u))>>16; return (short)r; }
__device__ __forceinline__ float bf2f(unsigned s){ return __uint_as_float(s<<16); }

// ---------------- K0: tiny prep (1 block) ----------------
// v_x[h][k] = sum_d attn_x[h][d]*W_x[h*32+d][k]; Wts/Wtd transposes (f32); We^T in bf16
__global__ __launch_bounds__(256) void prep_kernel(
    const float* __restrict__ Ws, const float* __restrict__ Wd, const float* __restrict__ We,
    const float* __restrict__ as_, const float* __restrict__ ad_, const float* __restrict__ ae_,
    float* __restrict__ vs, float* __restrict__ vd, float* __restrict__ ve,
    float* __restrict__ Wts, float* __restrict__ Wtd, unsigned short* __restrict__ WeTbf)
{
  int t = threadIdx.x;
  for (int idx = t; idx < HH*DINC; idx += 256) {
    int h = idx >> 7, k = idx & 127;
    float s1=0.f, s2=0.f, s3=0.f;
    for (int d=0; d<32; ++d) {
      int r = h*32 + d;
      s1 += as_[h*32+d] * Ws[r*DINC + k];
      s2 += ad_[h*32+d] * Wd[r*DINC + k];
      s3 += ae_[h*32+d] * We[r*DINC + k];
    }
    vs[idx] = s1; vd[idx] = s2; ve[idx] = s3;
  }
  for (int idx = t; idx < DINC*OUTC; idx += 256) {
    int j = idx >> 7, k = idx & 127;
    Wts[k*OUTC + j] = Ws[idx];
    Wtd[k*OUTC + j] = Wd[idx];
    int kk = idx >> 7, jj = idx & 127;         // WeTbf[k][j] = We[j][k]
    WeTbf[idx] = (unsigned short)f2bf(We[jj*DINC + kk]);
  }
}

// ---------------- K1: per-node h_src, h_dst(->out), e_src, e_dst ----------------
#define NT 32
__global__ __launch_bounds__(256) void node_kernel(
    const float* __restrict__ X, const float* __restrict__ Wts, const float* __restrict__ Wtd,
    const float* __restrict__ vs, const float* __restrict__ vd,
    float* __restrict__ hsrc, float* __restrict__ out,
    float* __restrict__ esrc, float* __restrict__ edst, int N)
{
  __shared__ float Xs[NT][DINC+1];
  __shared__ float vsh[2][HH][DINC];
  int t = threadIdx.x;
  int n0 = blockIdx.x * NT;

  for (int idx = t; idx < NT*DINC; idx += 256) {
    int n = idx >> 7, k = idx & 127;
    float v = 0.f;
    if (n0 + n < N) v = X[(long)(n0+n)*DINC + k];
    Xs[n][k] = v;
  }
  for (int idx = t; idx < HH*DINC; idx += 256) {
    ((float*)vsh)[idx]           = vs[idx];
    ((float*)vsh)[HH*DINC + idx] = vd[idx];
  }
  __syncthreads();

  int mat = t >> 7;
  int jq  = (t & 31) * 4;
  int r0  = (t >> 5) & 3;
  const float* Wt = mat ? Wtd : Wts;
  f32x4 acc[8];
  #pragma unroll
  for (int i=0;i<8;i++) acc[i] = (f32x4){0,0,0,0};

  for (int k=0; k<DINC; ++k) {
    f32x4 w4 = *(const f32x4*)(Wt + k*OUTC + jq);
    #pragma unroll
    for (int i=0;i<8;i++) acc[i] += w4 * Xs[r0 + i*4][k];
  }
  float* dstp = mat ? out : hsrc;
  #pragma unroll
  for (int i=0;i<8;i++) {
    int n = n0 + r0 + i*4;
    if (n < N) *(f32x4*)(dstp + (long)n*OUTC + jq) = acc[i];
  }
  int path = t >> 7, h = (t >> 5) & 3, nl = t & 31;
  int n = n0 + nl;
  if (n < N) {
    const float* vv = vsh[path][h];
    float s = 0.f;
    for (int k=0; k<DINC; ++k) s += Xs[nl][k] * vv[k];
    (path ? edst : esrc)[(long)n*HH + h] = s;
  }
}

// ---------------- CSR build ----------------
__global__ __launch_bounds__(256) void hist_kernel(const int* __restrict__ dst, int* __restrict__ deg, int E)
{
  int e = blockIdx.x*256 + threadIdx.x;
  if (e < E) atomicAdd(deg + dst[e], 1);
}

__global__ __launch_bounds__(256) void scan_kernel(const int* __restrict__ deg,
                                                   int* __restrict__ off, int* __restrict__ cursor, int N)
{
  __shared__ int part[256];
  int t = threadIdx.x;
  int chunk = (N + 255) / 256;
  int b = t*chunk, e_ = min(N, b+chunk);
  int s = 0;
  for (int i=b; i<e_; ++i) s += deg[i];
  part[t] = s;
  __syncthreads();
  if (t == 0) {
    int r = 0;
    for (int i=0; i<256; ++i) { int v = part[i]; part[i] = r; r += v; }
    off[N] = r;
  }
  __syncthreads();
  int r = part[t];
  for (int i=b; i<e_; ++i) { off[i] = r; cursor[i] = r; r += deg[i]; }
}

__global__ __launch_bounds__(256) void scatter_kernel(
    const int* __restrict__ src, const int* __restrict__ dst,
    int* __restrict__ cursor, unsigned long long* __restrict__ csr, int E)
{
  int e = blockIdx.x*256 + threadIdx.x;
  if (e >= E) return;
  int d = dst[e];
  int p = atomicAdd(cursor + d, 1);
  csr[p] = ((unsigned long long)(unsigned)src[e] << 32) | (unsigned)e;
}

// ---------------- K2: per-edge logits e_edge = Xe . ve[h] ----------------
__global__ __launch_bounds__(256) void edge_logits(
    const float* __restrict__ Xe, const float* __restrict__ ve,
    float* __restrict__ eedge, int E)
{
  int t = threadIdx.x;
  long e = (long)blockIdx.x * 8 + (t >> 5);
  int k4 = (t & 31) * 4;
  float a0=0.f, a1=0.f, a2=0.f, a3=0.f;
  if (e < E) {
    f32x4 x4 = *(const f32x4*)(Xe + e*DINC + k4);
    f32x4 v0 = *(const f32x4*)(ve + 0*DINC + k4);
    f32x4 v1 = *(const f32x4*)(ve + 1*DINC + k4);
    f32x4 v2 = *(const f32x4*)(ve + 2*DINC + k4);
    f32x4 v3 = *(const f32x4*)(ve + 3*DINC + k4);
    a0 = x4[0]*v0[0]+x4[1]*v0[1]+x4[2]*v0[2]+x4[3]*v0[3];
    a1 = x4[0]*v1[0]+x4[1]*v1[1]+x4[2]*v1[2]+x4[3]*v1[3];
    a2 = x4[0]*v2[0]+x4[1]*v2[1]+x4[2]*v2[2]+x4[3]*v2[3];
    a3 = x4[0]*v3[0]+x4[1]*v3[1]+x4[2]*v3[2]+x4[3]*v3[3];
  }
  #pragma unroll
  for (int s = 1; s <= 16; s <<= 1) {
    a0 += __shfl_xor(a0, s, 64);
    a1 += __shfl_xor(a1, s, 64);
    a2 += __shfl_xor(a2, s, 64);
    a3 += __shfl_xor(a3, s, 64);
  }
  if ((t & 31) == 0 && e < E) {
    f32x4 ee; ee[0]=a0; ee[1]=a1; ee[2]=a2; ee[3]=a3;
    *(f32x4*)(eedge + e*HH) = ee;
  }
}

// ---------------- K3: per-node CSR aggregation (no atomics) ----------------
// wave per node. 3 passes over in-edges: max, sum, accumulate.
// Edge path factored: Y[h] = sum a2*Xe[e]; finish with Y @ We_h^T (bf16 We^T in LDS).
__global__ __launch_bounds__(256) void aggregate_csr(
    const float* __restrict__ Xe, const float* __restrict__ hsrc,
    const float* __restrict__ eedge, const float* __restrict__ esrc,
    const float* __restrict__ edst,
    const unsigned long long* __restrict__ csr, const int* __restrict__ off,
    const unsigned short* __restrict__ WeTbf, float* __restrict__ out, int N)
{
  __shared__ float Ylds[4][HH][DINC];            // 8 KB
  __shared__ unsigned short Wl[DINC*OUTC];       // 32 KB, [k][j] bf16
  int t = threadIdx.x, wid = t >> 6, lane = t & 63;

  // stage We^T (bf16) into LDS: 32KB = 2048 x 16B
  {
    const u32x4* srcp = (const u32x4*)WeTbf;
    u32x4* dstp = (u32x4*)Wl;
    #pragma unroll
    for (int i = 0; i < 8; ++i) dstp[t + 256*i] = srcp[t + 256*i];
  }

  int n = blockIdx.x*4 + wid;
  bool valid = (n < N);
  int beg = 0, end = 0;
  if (valid) { beg = off[n]; end = off[n+1]; }

  int c = lane & 7, g = lane >> 3;               // 8 edges in flight for passes A/B
  float ed_c = valid ? edst[(long)n*HH + (c & 3)] : 0.f;

  // pass A: per-(path,head) max over edges
  float mloc = -3.402823e38f;
  for (int p = beg + g; p < end; p += 8) {
    unsigned long long pk = csr[p];
    int s_ = (int)(pk >> 32), eid = (int)(unsigned)pk;
    float x = (c < 4) ? esrc[(long)s_*HH + c] : eedge[(long)eid*HH + (c-4)];
    mloc = fmaxf(mloc, leaky(x + ed_c));
  }
  mloc = fmaxf(mloc, __shfl_xor(mloc, 8, 64));
  mloc = fmaxf(mloc, __shfl_xor(mloc, 16, 64));
  mloc = fmaxf(mloc, __shfl_xor(mloc, 32, 64));

  // pass B: exp-sum
  float sloc = 0.f;
  for (int p = beg + g; p < end; p += 8) {
    unsigned long long pk = csr[p];
    int s_ = (int)(pk >> 32), eid = (int)(unsigned)pk;
    float x = (c < 4) ? esrc[(long)s_*HH + c] : eedge[(long)eid*HH + (c-4)];
    sloc += __expf(leaky(x + ed_c) - mloc);
  }
  sloc += __shfl_xor(sloc, 8, 64);
  sloc += __shfl_xor(sloc, 16, 64);
  sloc += __shfl_xor(sloc, 32, 64);
  float is = 1.f / sloc;

  // pass C: accumulate. lane owns output cols 2*lane, 2*lane+1 (head hl)
  int hl = lane >> 4;
  f32x2 acc = valid ? *(const f32x2*)(out + (long)n*OUTC + 2*lane) : (f32x2){0.f,0.f};
  f32x2 Y0={0,0}, Y1={0,0}, Y2={0,0}, Y3={0,0};
  for (int p = beg; p < end; ++p) {
    unsigned long long pk = csr[p];
    int s_ = (int)(pk >> 32), eid = (int)(unsigned)pk;
    float aval = 0.f;
    if (lane < 8) {
      float x = (lane < 4) ? esrc[(long)s_*HH + lane] : eedge[(long)eid*HH + (lane-4)];
      aval = __expf(leaky(x + ed_c) - mloc) * is;
    }
    float a1h = __shfl(aval, hl, 64);
    float b0 = __shfl(aval, 4, 64), b1 = __shfl(aval, 5, 64);
    float b2 = __shfl(aval, 6, 64), b3 = __shfl(aval, 7, 64);
    f32x2 xe = *(const f32x2*)(Xe   + (long)eid*DINC + 2*lane);
    f32x2 hs = *(const f32x2*)(hsrc + (long)s_*OUTC + 2*lane);
    acc += a1h * hs;
    Y0 += b0 * xe; Y1 += b1 * xe; Y2 += b2 * xe; Y3 += b3 * xe;
  }

  // Y -> LDS (own-wave region)
  *(f32x2*)&Ylds[wid][0][2*lane] = Y0;
  *(f32x2*)&Ylds[wid][1][2*lane] = Y1;
  *(f32x2*)&Ylds[wid][2][2*lane] = Y2;
  *(f32x2*)&Ylds[wid][3][2*lane] = Y3;
  __syncthreads();   // covers Wl staging + Ylds

  // finish: out[n, j] = acc + sum_k Y[hl][k] * We[j,k]
  const float* yp = Ylds[wid][hl];
  int j0 = 2*lane;
  float f0 = 0.f, f1 = 0.f;
  #pragma unroll 8
  for (int k = 0; k < DINC; ++k) {
    unsigned wu = *(const unsigned*)&Wl[k*OUTC + j0];
    float y = yp[k];
    f0 += y * bf2f(wu & 0xffffu);
    f1 += y * bf2f(wu >> 16);
  }
  if (valid) {
    out[(long)n*OUTC + j0]     = acc[0] + f0;
    out[(long)n*OUTC + j0 + 1] = acc[1] + f1;
  }
}

extern "C" void kernel_launch(void* const* d_in, const int* in_sizes, int n_in,
                              void* d_out, int out_size, void* d_ws, size_t ws_size,
                              hipStream_t stream) {
  const float* X   = (const float*)d_in[0];
  const float* Xe  = (const float*)d_in[1];
  const float* Ws  = (const float*)d_in[2];
  const float* Wd  = (const float*)d_in[3];
  const float* We  = (const float*)d_in[4];
  const float* as_ = (const float*)d_in[5];
  const float* ad_ = (const float*)d_in[6];
  const float* ae_ = (const float*)d_in[7];
  const int* src   = (const int*)d_in[8];
  const int* dst   = (const int*)d_in[9];
  int N = in_sizes[0] / DINC;
  int E = in_sizes[8];
  float* out = (float*)d_out;

  char* ws = (char*)d_ws;
  size_t o_hsrc = 0;
  size_t o_esrc = o_hsrc + (size_t)N*OUTC*4;
  size_t o_edst = o_esrc + (size_t)N*HH*4;
  size_t o_eedge= o_edst + (size_t)N*HH*4;
  size_t o_vs   = o_eedge+ (size_t)E*HH*4;
  size_t o_vd   = o_vs   + (size_t)HH*DINC*4;
  size_t o_ve   = o_vd   + (size_t)HH*DINC*4;
  size_t o_wts  = o_ve   + (size_t)HH*DINC*4;
  size_t o_wtd  = o_wts  + (size_t)DINC*OUTC*4;
  size_t o_webf = o_wtd  + (size_t)DINC*OUTC*4;
  size_t o_deg  = o_webf + (size_t)DINC*OUTC*2;
  size_t o_off  = o_deg  + (size_t)N*4;
  size_t o_cur  = o_off  + (size_t)(N+2)*4;
  size_t o_csr  = o_cur  + (size_t)N*4;
  o_csr = (o_csr + 7) & ~(size_t)7;

  float* hsrc  = (float*)(ws + o_hsrc);
  float* esrc  = (float*)(ws + o_esrc);
  float* edstp = (float*)(ws + o_edst);
  float* eedge = (float*)(ws + o_eedge);
  float* vs    = (float*)(ws + o_vs);
  float* vd    = (float*)(ws + o_vd);
  float* ve    = (float*)(ws + o_ve);
  float* wts   = (float*)(ws + o_wts);
  float* wtd   = (float*)(ws + o_wtd);
  unsigned short* webf = (unsigned short*)(ws + o_webf);
  int* deg     = (int*)(ws + o_deg);
  int* off     = (int*)(ws + o_off);
  int* cursor  = (int*)(ws + o_cur);
  unsigned long long* csr = (unsigned long long*)(ws + o_csr);

  hipMemsetAsync(deg, 0, (size_t)N*4, stream);

  prep_kernel<<<1, 256, 0, stream>>>(Ws, Wd, We, as_, ad_, ae_, vs, vd, ve, wts, wtd, webf);
  node_kernel<<<(N + NT - 1)/NT, 256, 0, stream>>>(X, wts, wtd, vs, vd, hsrc, out, esrc, edstp, N);
  hist_kernel<<<(E + 255)/256, 256, 0, stream>>>(dst, deg, E);
  scan_kernel<<<1, 256, 0, stream>>>(deg, off, cursor, N);
  scatter_kernel<<<(E + 255)/256, 256, 0, stream>>>(src, dst, cursor, csr, E);
  edge_logits<<<(E + 7)/8, 256, 0, stream>>>(Xe, ve, eedge, E);
  aggregate_csr<<<(N + 3)/4, 256, 0, stream>>>(Xe, hsrc, eedge, esrc, edstp, csr, off, webf, out, N);
}